// Round 1
// baseline (632.285 us; speedup 1.0000x reference)
//
#include <hip/hip_runtime.h>
#include <math.h>

#define ROWS 64
#define TLEN 64000
#define NFR 251
#define NMELS 80
#define NFB 131072            // big FFT length (>= 2*T-1 -> exact linear conv)
#define PI2F 6.28318530717958647692f

// banked double accumulators:
// 0 S_dt  1 S_rt  2 S_sp  3..6 E0..E3  7 S_mag  8 S_cos  9 S_mel  10 S_c
__device__ double g_part[64][12];

__device__ inline void atomAddD(double* p, double v){
  __hip_atomic_fetch_add(p, v, __ATOMIC_RELAXED, __HIP_MEMORY_SCOPE_AGENT);
}

__device__ inline unsigned brevn(unsigned x, int bits){ return __brev(x) >> (32 - bits); }

__device__ inline float wred(float v){
#pragma unroll
  for (int o = 32; o > 0; o >>= 1) v += __shfl_down(v, o, 64);
  return v;
}

// nrows independent in-place radix-2 DIF FFTs of length L (power of 2) in LDS.
// sign = -1 forward, +1 inverse (unnormalized). Output bit-reversed: X[k] at brevn(k).
__device__ inline void fft_lds(float2* B, int rowStride, int nrows, int L, int log2L,
                               float sign, int tid, int nth){
  int halfbits = log2L - 1;
  const int nbf = nrows << (log2L - 1);
  const int umask = (1 << (log2L - 1)) - 1;
  for (int len = L; len >= 2; len >>= 1, --halfbits){
    int half = len >> 1;
    float angstep = sign * (PI2F / (float)len);
    for (int t = tid; t < nbf; t += nth){
      int f = t >> (log2L - 1);
      int u = t & umask;
      int g = u >> halfbits;
      int j = u & (half - 1);
      float2* p = B + f*rowStride + (g << (halfbits + 1)) + j;
      float2 a = p[0], c = p[half];
      float sx = a.x + c.x, sy = a.y + c.y;
      float dx = a.x - c.x, dy = a.y - c.y;
      float sn, cs; sincosf(angstep * (float)j, &sn, &cs);
      p[0] = make_float2(sx, sy);
      p[half] = make_float2(dx*cs - dy*sn, dx*sn + dy*cs);
    }
    __syncthreads();
  }
}

extern "C" __global__ void __launch_bounds__(256) k_init(){
  int t = blockIdx.x*256 + threadIdx.x;
  if (t < 64*12) ((double*)g_part)[t] = 0.0;
}

// ---------------- time-domain losses + rir segment energies ----------------
extern "C" __global__ void __launch_bounds__(256) k_time(
    const float* __restrict__ pd, const float* __restrict__ td,
    const float* __restrict__ pr, const float* __restrict__ tr){
  const int NTOT = ROWS*TLEN;
  int stride = gridDim.x * 256;
  float sdt=0.f, srt=0.f, ssp=0.f, e0=0.f, e1=0.f, e2=0.f, e3=0.f;
  for (int i = blockIdx.x*256 + threadIdx.x; i < NTOT; i += stride){
    float d = pd[i] - td[i]; sdt += fabsf(d);
    float p = pr[i];
    float q = p - tr[i];     srt += fabsf(q);
    ssp += fabsf(p);
    int tloc = i % TLEN;
    int seg = tloc / 16000;
    float p2 = p*p;
    if (seg == 0) e0 += p2; else if (seg == 1) e1 += p2;
    else if (seg == 2) e2 += p2; else e3 += p2;
  }
  sdt = wred(sdt); srt = wred(srt); ssp = wred(ssp);
  e0 = wred(e0); e1 = wred(e1); e2 = wred(e2); e3 = wred(e3);
  if ((threadIdx.x & 63) == 0){
    int bank = (blockIdx.x*4 + (threadIdx.x >> 6)) & 63;
    atomAddD(&g_part[bank][0], (double)sdt);
    atomAddD(&g_part[bank][1], (double)srt);
    atomAddD(&g_part[bank][2], (double)ssp);
    atomAddD(&g_part[bank][3], (double)e0);
    atomAddD(&g_part[bank][4], (double)e1);
    atomAddD(&g_part[bank][5], (double)e2);
    atomAddD(&g_part[bank][6], (double)e3);
  }
}

// ---------------- fused STFT (freq + mel) losses ----------------
// one block per (row, frame); pred as real, target as imag of one 1024-pt FFT
extern "C" __global__ void __launch_bounds__(256) k_stft(
    const float* __restrict__ pd, const float* __restrict__ td){
  __shared__ float2 S[1024];
  __shared__ float pp[513], tt[513], fpts[82], red[12];
  int blk = blockIdx.x;
  int r = blk / NFR, fr = blk - r*NFR;
  int tid = threadIdx.x;
  const float* pdr = pd + (size_t)r*TLEN;
  const float* tdr = td + (size_t)r*TLEN;
  int base = fr*256 - 512;
  for (int j = tid; j < 1024; j += 256){
    int g = base + j;
    g = (g < 0) ? -g : ((g >= TLEN) ? (2*TLEN - 2 - g) : g);
    float w = 0.5f - 0.5f*cosf((PI2F/1024.0f)*(float)j);   // periodic hann
    S[j] = make_float2(pdr[g]*w, tdr[g]*w);
  }
  for (int i = tid; i < 82; i += 256){
    float maxmel = 2595.0f * log10f(1.0f + 8000.0f/700.0f);
    float m = maxmel * (float)i * (1.0f/81.0f);
    fpts[i] = 700.0f * (exp10f(m * (1.0f/2595.0f)) - 1.0f);
  }
  __syncthreads();
  fft_lds(S, 0, 1, 1024, 10, -1.0f, tid, 256);
  const float scale = 0.05103103630798288f;  // 1/sqrt(sum(hann^2)) = 1/sqrt(384)
  float magp = 0.f, cosp = 0.f;
  for (int k = tid; k <= 512; k += 256){
    float2 z  = S[brevn((unsigned)k, 10)];
    float2 zm = S[brevn((unsigned)((1024 - k) & 1023), 10)];
    // P = (Z + conj(Zm))/2 ; T = (Z - conj(Zm))/(2i)
    float px = 0.5f*(z.x + zm.x), py = 0.5f*(z.y - zm.y);
    float tx = 0.5f*(z.y + zm.y), ty = -0.5f*(z.x - zm.x);
    px *= scale; py *= scale; tx *= scale; ty *= scale;
    float ppk = px*px + py*py, ttk = tx*tx + ty*ty;
    magp += fabsf(sqrtf(ppk) - sqrtf(ttk));
    float den = ppk*ttk;
    cosp += (den > 0.f) ? (px*tx + py*ty) * rsqrtf(den) : 1.0f;
    pp[k] = ppk; tt[k] = ttk;
  }
  __syncthreads();
  float melp = 0.f;
  if (tid < NMELS){
    float f0 = fpts[tid], f1 = fpts[tid+1], f2 = fpts[tid+2];
    float i1 = 1.0f/(f1 - f0), i2 = 1.0f/(f2 - f1);
    const float df = 15.625f;           // 8000/512, exact
    int lo = (int)ceilf(f0 * (1.0f/df));  if (lo < 0) lo = 0;
    int hi = (int)floorf(f2 * (1.0f/df)); if (hi > 512) hi = 512;
    float pm = 0.f, tm = 0.f;
    for (int k = lo; k <= hi; ++k){
      float frq = df*(float)k;
      float c = fminf((frq - f0)*i1, (f2 - frq)*i2);
      c = fmaxf(c, 0.f);
      pm += c*pp[k]; tm += c*tt[k];
    }
    melp = fabsf(logf(pm + 1e-8f) - logf(tm + 1e-8f));
  }
  float m1 = wred(magp), m2 = wred(cosp), m3 = wred(melp);
  int lane = tid & 63, wid = tid >> 6;
  if (lane == 0){ red[wid] = m1; red[4+wid] = m2; red[8+wid] = m3; }
  __syncthreads();
  if (tid == 0){
    int bank = blk & 63;
    atomAddD(&g_part[bank][7], (double)(red[0]+red[1]+red[2]+red[3]));
    atomAddD(&g_part[bank][8], (double)(red[4]+red[5]+red[6]+red[7]));
    atomAddD(&g_part[bank][9], (double)(red[8]+red[9]+red[10]+red[11]));
  }
}

// ---------------- consistency: four-step FFT of 131072 = 128 x 1024 ----------------
// layout per row in ws: buf[k2*128 + n1]  (after fwd1: Y[n1][k2] stored transposed)
// fwd1: for each n1, 1024-pt FFT over n2 of z[n1+128*n2]=pd+i*pr, * W_NF^(-n1*k2)
extern "C" __global__ void __launch_bounds__(256) k_fwd1(
    const float* __restrict__ pd, const float* __restrict__ pr,
    float2* __restrict__ buf, int row0){
  __shared__ float2 S[8][1024];
  int rl = blockIdx.y;
  int r = row0 + rl;
  int n1_0 = blockIdx.x * 8;
  int tid = threadIdx.x;
  const float* a = pd + (size_t)r*TLEN;
  const float* b = pr + (size_t)r*TLEN;
  for (int idx = tid; idx < 8192; idx += 256){
    int f = idx & 7, n2 = idx >> 3;
    float re = 0.f, im = 0.f;
    if (n2 < 500){                       // n = n1+128*n2 < 64000  <=>  n2 < 500
      int n = n1_0 + f + 128*n2;
      re = a[n]; im = b[n];
    }
    S[f][n2] = make_float2(re, im);
  }
  __syncthreads();
  fft_lds(&S[0][0], 1024, 8, 1024, 10, -1.0f, tid, 256);
  float2* outr = buf + (size_t)rl * NFB;
  const float tw = -(PI2F / (float)NFB);
  for (int idx = tid; idx < 8192; idx += 256){
    int f = idx & 7, k2 = idx >> 3;
    int n1 = n1_0 + f;
    float2 v = S[f][brevn((unsigned)k2, 10)];
    float sn, cs; sincosf(tw * (float)(n1*k2), &sn, &cs);
    outr[(size_t)k2*128 + n1] = make_float2(v.x*cs - v.y*sn, v.x*sn + v.y*cs);
  }
}

// fwd2: per k2-row, 128-pt FFT over n1 -> Z[k2 + 1024*k1] stored at [k2*128+k1], in place
extern "C" __global__ void __launch_bounds__(256) k_fwd2(float2* __restrict__ buf){
  __shared__ float2 S[8][128];
  int rl = blockIdx.y;
  float2* rowp = buf + (size_t)rl*NFB + (size_t)blockIdx.x*1024;
  int tid = threadIdx.x;
  for (int idx = tid; idx < 1024; idx += 256) S[idx>>7][idx&127] = rowp[idx];
  __syncthreads();
  fft_lds(&S[0][0], 128, 8, 128, 7, -1.0f, tid, 256);
  for (int idx = tid; idx < 1024; idx += 256){
    int f = idx >> 7, k1 = idx & 127;
    rowp[f*128 + k1] = S[f][brevn((unsigned)k1, 7)];
  }
}

// pointwise: split packed spectrum Z into D,R; C = D*R; write C[k] and conj at mirror.
// thread owns pair (k, NF-k); k = k2 + 1024*k1, addr = k2*128 + k1; cover k1 in [0,64)
extern "C" __global__ void __launch_bounds__(256) k_point(float2* __restrict__ buf){
  int rl = blockIdx.y;
  int t = blockIdx.x*256 + threadIdx.x;   // 0..65535
  int k2 = t >> 6, k1 = t & 63;
  float2* rowp = buf + (size_t)rl*NFB;
  if (k2 == 0){
    if (k1 == 0){
      float2 z0 = rowp[0];  rowp[0]  = make_float2(z0.x*z0.y, 0.f);   // k=0
      float2 zh = rowp[64]; rowp[64] = make_float2(zh.x*zh.y, 0.f);   // k=NF/2
    } else {
      float2 z = rowp[k1], zm = rowp[128 - k1];
      float Dx = 0.5f*(z.x + zm.x), Dy = 0.5f*(z.y - zm.y);
      float Rx = 0.5f*(z.y + zm.y), Ry = -0.5f*(z.x - zm.x);
      float Cx = Dx*Rx - Dy*Ry, Cy = Dx*Ry + Dy*Rx;
      rowp[k1]       = make_float2(Cx,  Cy);
      rowp[128 - k1] = make_float2(Cx, -Cy);
    }
  } else {
    int a  = k2*128 + k1;
    int am = (1024 - k2)*128 + (127 - k1);
    float2 z = rowp[a], zm = rowp[am];
    float Dx = 0.5f*(z.x + zm.x), Dy = 0.5f*(z.y - zm.y);
    float Rx = 0.5f*(z.y + zm.y), Ry = -0.5f*(z.x - zm.x);
    float Cx = Dx*Rx - Dy*Ry, Cy = Dx*Ry + Dy*Rx;
    rowp[a]  = make_float2(Cx,  Cy);
    rowp[am] = make_float2(Cx, -Cy);
  }
}

// inv1: per k2-row, inverse 128-pt FFT over k1 -> B[k2][n1], * W_NF^(+n1*k2), in place
extern "C" __global__ void __launch_bounds__(256) k_inv1(float2* __restrict__ buf){
  __shared__ float2 S[8][128];
  int rl = blockIdx.y;
  int k2_0 = blockIdx.x * 8;
  float2* rowp = buf + (size_t)rl*NFB + (size_t)k2_0*128;
  int tid = threadIdx.x;
  for (int idx = tid; idx < 1024; idx += 256) S[idx>>7][idx&127] = rowp[idx];
  __syncthreads();
  fft_lds(&S[0][0], 128, 8, 128, 7, +1.0f, tid, 256);
  const float tw = PI2F / (float)NFB;
  for (int idx = tid; idx < 1024; idx += 256){
    int f = idx >> 7, n1 = idx & 127;
    int k2 = k2_0 + f;
    float2 v = S[f][brevn((unsigned)n1, 7)];
    float sn, cs; sincosf(tw * (float)(n1*k2), &sn, &cs);
    rowp[f*128 + n1] = make_float2(v.x*cs - v.y*sn, v.x*sn + v.y*cs);
  }
}

// inv2: per n1, inverse 1024-pt FFT over k2 -> c[n1+128*n2]; fuse |c - mix| reduction
extern "C" __global__ void __launch_bounds__(256) k_inv2(
    const float* __restrict__ mix, float2* __restrict__ buf, int row0){
  __shared__ float2 S[8][1024];
  int rl = blockIdx.y;
  int r = row0 + rl;
  int n1_0 = blockIdx.x * 8;
  int tid = threadIdx.x;
  float2* rowp = buf + (size_t)rl*NFB;
  for (int idx = tid; idx < 8192; idx += 256){
    int f = idx & 7, k2 = idx >> 3;
    S[f][k2] = rowp[(size_t)k2*128 + n1_0 + f];
  }
  __syncthreads();
  fft_lds(&S[0][0], 1024, 8, 1024, 10, +1.0f, tid, 256);
  const float* mr = mix + (size_t)r*TLEN;
  const float invn = 1.0f/(float)NFB;
  float acc = 0.f;
  for (int idx = tid; idx < 8192; idx += 256){
    int f = idx & 7, n2 = idx >> 3;
    if (n2 < 500){
      float c = S[f][brevn((unsigned)n2, 10)].x * invn;
      int n = n1_0 + f + 128*n2;
      acc += fabsf(c - mr[n]);
    }
  }
  __syncthreads();
  float v = wred(acc);
  float* Sf = (float*)&S[0][0];   // reuse LDS for the cross-wave reduce
  int lane = tid & 63, wid = tid >> 6;
  if (lane == 0) Sf[wid] = v;
  __syncthreads();
  if (tid == 0){
    int bank = (blockIdx.x + blockIdx.y*16) & 63;
    atomAddD(&g_part[bank][10], (double)(Sf[0]+Sf[1]+Sf[2]+Sf[3]));
  }
}

// ---------------- combine ----------------
extern "C" __global__ void __launch_bounds__(64) k_finalize(float* __restrict__ out){
  __shared__ double s[12];
  int t = threadIdx.x;
  if (t < 12){
    double v = 0.0;
    for (int b = 0; b < 64; ++b) v += g_part[b][t];
    s[t] = v;
  }
  __syncthreads();
  if (t == 0){
    double dt = s[0] / 4096000.0;
    double rt = s[1] / 4096000.0;
    double sp = s[2] / 4096000.0;
    double e0 = s[3] / 1024000.0, e1 = s[4] / 1024000.0;
    double e2 = s[5] / 1024000.0, e3 = s[6] / 1024000.0;
    double dec = fmax(e1 - 0.8*e0, 0.0) + fmax(e2 - 0.8*e1, 0.0) + fmax(e3 - 0.8*e2, 0.0);
    double c1 = 8240832.0;              // 64*513*251
    double freq = s[7]/c1 + 0.1*(1.0 - s[8]/c1);
    double mel  = s[9] / 1285120.0;     // 64*80*251
    double cons = s[10] / 4096000.0;
    double total = 3.0*(dt + 0.5*freq + 0.3*mel)
                 + (rt + 0.1*(sp + dec))
                 + 0.2*cons;
    out[0] = (float)total;
  }
}

extern "C" void kernel_launch(void* const* d_in, const int* in_sizes, int n_in,
                              void* d_out, int out_size, void* d_ws, size_t ws_size,
                              hipStream_t stream){
  const float* pd = (const float*)d_in[0];
  const float* pr = (const float*)d_in[1];
  const float* td = (const float*)d_in[2];
  const float* tr = (const float*)d_in[3];
  const float* mx = (const float*)d_in[4];
  float* out = (float*)d_out;
  float2* buf = (float2*)d_ws;

  size_t rowBytes = (size_t)NFB * sizeof(float2);     // 1 MiB per row
  int maxrows = (int)(ws_size / rowBytes);
  if (maxrows > ROWS) maxrows = ROWS;
  if (maxrows < 1) maxrows = 1;

  hipLaunchKernelGGL(k_init, dim3(3), dim3(256), 0, stream);
  hipLaunchKernelGGL(k_time, dim3(2048), dim3(256), 0, stream, pd, td, pr, tr);
  hipLaunchKernelGGL(k_stft, dim3(ROWS*NFR), dim3(256), 0, stream, pd, td);
  for (int row0 = 0; row0 < ROWS; row0 += maxrows){
    int nr = ROWS - row0; if (nr > maxrows) nr = maxrows;
    hipLaunchKernelGGL(k_fwd1,  dim3(16, nr),  dim3(256), 0, stream, pd, pr, buf, row0);
    hipLaunchKernelGGL(k_fwd2,  dim3(128, nr), dim3(256), 0, stream, buf);
    hipLaunchKernelGGL(k_point, dim3(256, nr), dim3(256), 0, stream, buf);
    hipLaunchKernelGGL(k_inv1,  dim3(128, nr), dim3(256), 0, stream, buf);
    hipLaunchKernelGGL(k_inv2,  dim3(16, nr),  dim3(256), 0, stream, mx, buf, row0);
  }
  hipLaunchKernelGGL(k_finalize, dim3(1), dim3(64), 0, stream, out);
}

// Round 2
// 501.127 us; speedup vs baseline: 1.2617x; 1.2617x over previous
//
#include <hip/hip_runtime.h>
#include <math.h>

#define ROWS 64
#define TLEN 64000
#define NFR 251
#define NMELS 80
#define NFB 131072            // big FFT length (>= 2*T-1 -> exact linear conv)
#define PI2F 6.28318530717958647692f

// banked double accumulators:
// 0 S_dt  1 S_rt  2 S_sp  3..6 E0..E3  7 S_mag  8 S_cos  9 S_mel  10 S_c
__device__ double g_part[64][12];

__device__ inline void atomAddD(double* p, double v){
  __hip_atomic_fetch_add(p, v, __ATOMIC_RELAXED, __HIP_MEMORY_SCOPE_AGENT);
}

__device__ inline unsigned brevn(unsigned x, int bits){ return __brev(x) >> (32 - bits); }

// fast hardware sincos: v_sin_f32/v_cos_f32 via __sinf/__cosf (~3 VALU ops each)
__device__ inline void fsincos(float a, float* s, float* c){
  *s = __sinf(a); *c = __cosf(a);
}

__device__ inline float wred(float v){
#pragma unroll
  for (int o = 32; o > 0; o >>= 1) v += __shfl_down(v, o, 64);
  return v;
}

// nrows independent in-place radix-2 DIF FFTs of length L (power of 2) in LDS.
// sign = -1 forward, +1 inverse (unnormalized). Output bit-reversed: X[k] at brevn(k).
__device__ inline void fft_lds(float2* B, int rowStride, int nrows, int L, int log2L,
                               float sign, int tid, int nth){
  int halfbits = log2L - 1;
  const int nbf = nrows << (log2L - 1);
  const int umask = (1 << (log2L - 1)) - 1;
  for (int len = L; len >= 2; len >>= 1, --halfbits){
    int half = len >> 1;
    float angstep = sign * (PI2F / (float)len);
    for (int t = tid; t < nbf; t += nth){
      int f = t >> (log2L - 1);
      int u = t & umask;
      int g = u >> halfbits;
      int j = u & (half - 1);
      float2* p = B + f*rowStride + (g << (halfbits + 1)) + j;
      float2 a = p[0], c = p[half];
      float sx = a.x + c.x, sy = a.y + c.y;
      float dx = a.x - c.x, dy = a.y - c.y;
      float sn, cs; fsincos(angstep * (float)j, &sn, &cs);
      p[0] = make_float2(sx, sy);
      p[half] = make_float2(dx*cs - dy*sn, dx*sn + dy*cs);
    }
    __syncthreads();
  }
}

extern "C" __global__ void __launch_bounds__(256) k_init(){
  int t = blockIdx.x*256 + threadIdx.x;
  if (t < 64*12) ((double*)g_part)[t] = 0.0;
}

// ---------------- time-domain losses + rir segment energies ----------------
extern "C" __global__ void __launch_bounds__(256) k_time(
    const float* __restrict__ pd, const float* __restrict__ td,
    const float* __restrict__ pr, const float* __restrict__ tr){
  const int NTOT = ROWS*TLEN;
  int stride = gridDim.x * 256;
  float sdt=0.f, srt=0.f, ssp=0.f, e0=0.f, e1=0.f, e2=0.f, e3=0.f;
  for (int i = blockIdx.x*256 + threadIdx.x; i < NTOT; i += stride){
    float d = pd[i] - td[i]; sdt += fabsf(d);
    float p = pr[i];
    float q = p - tr[i];     srt += fabsf(q);
    ssp += fabsf(p);
    int tloc = i % TLEN;
    int seg = tloc / 16000;
    float p2 = p*p;
    if (seg == 0) e0 += p2; else if (seg == 1) e1 += p2;
    else if (seg == 2) e2 += p2; else e3 += p2;
  }
  sdt = wred(sdt); srt = wred(srt); ssp = wred(ssp);
  e0 = wred(e0); e1 = wred(e1); e2 = wred(e2); e3 = wred(e3);
  if ((threadIdx.x & 63) == 0){
    int bank = (blockIdx.x*4 + (threadIdx.x >> 6)) & 63;
    atomAddD(&g_part[bank][0], (double)sdt);
    atomAddD(&g_part[bank][1], (double)srt);
    atomAddD(&g_part[bank][2], (double)ssp);
    atomAddD(&g_part[bank][3], (double)e0);
    atomAddD(&g_part[bank][4], (double)e1);
    atomAddD(&g_part[bank][5], (double)e2);
    atomAddD(&g_part[bank][6], (double)e3);
  }
}

// ---------------- fused STFT (freq + mel) losses ----------------
// one block per (row, frame); pred as real, target as imag of one 1024-pt FFT
extern "C" __global__ void __launch_bounds__(256) k_stft(
    const float* __restrict__ pd, const float* __restrict__ td){
  __shared__ float2 S[1024];
  __shared__ float pp[513], tt[513], fpts[82], red[12];
  int blk = blockIdx.x;
  int r = blk / NFR, fr = blk - r*NFR;
  int tid = threadIdx.x;
  const float* pdr = pd + (size_t)r*TLEN;
  const float* tdr = td + (size_t)r*TLEN;
  int base = fr*256 - 512;
  for (int j = tid; j < 1024; j += 256){
    int g = base + j;
    g = (g < 0) ? -g : ((g >= TLEN) ? (2*TLEN - 2 - g) : g);
    float w = 0.5f - 0.5f*__cosf((PI2F/1024.0f)*(float)j);   // periodic hann
    S[j] = make_float2(pdr[g]*w, tdr[g]*w);
  }
  for (int i = tid; i < 82; i += 256){
    float maxmel = 2595.0f * log10f(1.0f + 8000.0f/700.0f);
    float m = maxmel * (float)i * (1.0f/81.0f);
    fpts[i] = 700.0f * (exp10f(m * (1.0f/2595.0f)) - 1.0f);
  }
  __syncthreads();
  fft_lds(S, 0, 1, 1024, 10, -1.0f, tid, 256);
  const float scale = 0.05103103630798288f;  // 1/sqrt(sum(hann^2)) = 1/sqrt(384)
  float magp = 0.f, cosp = 0.f;
  for (int k = tid; k <= 512; k += 256){
    float2 z  = S[brevn((unsigned)k, 10)];
    float2 zm = S[brevn((unsigned)((1024 - k) & 1023), 10)];
    // P = (Z + conj(Zm))/2 ; T = (Z - conj(Zm))/(2i)
    float px = 0.5f*(z.x + zm.x), py = 0.5f*(z.y - zm.y);
    float tx = 0.5f*(z.y + zm.y), ty = -0.5f*(z.x - zm.x);
    px *= scale; py *= scale; tx *= scale; ty *= scale;
    float ppk = px*px + py*py, ttk = tx*tx + ty*ty;
    magp += fabsf(sqrtf(ppk) - sqrtf(ttk));
    float den = ppk*ttk;
    cosp += (den > 0.f) ? (px*tx + py*ty) * rsqrtf(den) : 1.0f;
    pp[k] = ppk; tt[k] = ttk;
  }
  __syncthreads();
  float melp = 0.f;
  if (tid < NMELS){
    float f0 = fpts[tid], f1 = fpts[tid+1], f2 = fpts[tid+2];
    float i1 = 1.0f/(f1 - f0), i2 = 1.0f/(f2 - f1);
    const float df = 15.625f;           // 8000/512, exact
    int lo = (int)ceilf(f0 * (1.0f/df));  if (lo < 0) lo = 0;
    int hi = (int)floorf(f2 * (1.0f/df)); if (hi > 512) hi = 512;
    float pm = 0.f, tm = 0.f;
    for (int k = lo; k <= hi; ++k){
      float frq = df*(float)k;
      float c = fminf((frq - f0)*i1, (f2 - frq)*i2);
      c = fmaxf(c, 0.f);
      pm += c*pp[k]; tm += c*tt[k];
    }
    melp = fabsf(logf(pm + 1e-8f) - logf(tm + 1e-8f));
  }
  float m1 = wred(magp), m2 = wred(cosp), m3 = wred(melp);
  int lane = tid & 63, wid = tid >> 6;
  if (lane == 0){ red[wid] = m1; red[4+wid] = m2; red[8+wid] = m3; }
  __syncthreads();
  if (tid == 0){
    int bank = blk & 63;
    atomAddD(&g_part[bank][7], (double)(red[0]+red[1]+red[2]+red[3]));
    atomAddD(&g_part[bank][8], (double)(red[4]+red[5]+red[6]+red[7]));
    atomAddD(&g_part[bank][9], (double)(red[8]+red[9]+red[10]+red[11]));
  }
}

// ---------------- consistency: four-step FFT of 131072 = 128 x 1024 ----------------
// layout per row in ws: buf[k2*128 + n1]  (after fwd1: Y[n1][k2] stored transposed)
// fwd1: for each n1, 1024-pt FFT over n2 of z[n1+128*n2]=pd+i*pr, * W_NF^(-n1*k2)
extern "C" __global__ void __launch_bounds__(256) k_fwd1(
    const float* __restrict__ pd, const float* __restrict__ pr,
    float2* __restrict__ buf, int row0){
  __shared__ float2 S[8][1024];
  int rl = blockIdx.y;
  int r = row0 + rl;
  int n1_0 = blockIdx.x * 8;
  int tid = threadIdx.x;
  const float* a = pd + (size_t)r*TLEN;
  const float* b = pr + (size_t)r*TLEN;
  for (int idx = tid; idx < 8192; idx += 256){
    int f = idx & 7, n2 = idx >> 3;
    float re = 0.f, im = 0.f;
    if (n2 < 500){                       // n = n1+128*n2 < 64000  <=>  n2 < 500
      int n = n1_0 + f + 128*n2;
      re = a[n]; im = b[n];
    }
    S[f][n2] = make_float2(re, im);
  }
  __syncthreads();
  fft_lds(&S[0][0], 1024, 8, 1024, 10, -1.0f, tid, 256);
  float2* outr = buf + (size_t)rl * NFB;
  const float tw = -(PI2F / (float)NFB);
  for (int idx = tid; idx < 8192; idx += 256){
    int f = idx & 7, k2 = idx >> 3;
    int n1 = n1_0 + f;
    float2 v = S[f][brevn((unsigned)k2, 10)];
    float sn, cs; fsincos(tw * (float)(n1*k2), &sn, &cs);
    outr[(size_t)k2*128 + n1] = make_float2(v.x*cs - v.y*sn, v.x*sn + v.y*cs);
  }
}

// fwd2: per k2-row, 128-pt FFT over n1 -> Z[k2 + 1024*k1] stored at [k2*128+k1], in place
extern "C" __global__ void __launch_bounds__(256) k_fwd2(float2* __restrict__ buf){
  __shared__ float2 S[8][128];
  int rl = blockIdx.y;
  float2* rowp = buf + (size_t)rl*NFB + (size_t)blockIdx.x*1024;
  int tid = threadIdx.x;
  for (int idx = tid; idx < 1024; idx += 256) S[idx>>7][idx&127] = rowp[idx];
  __syncthreads();
  fft_lds(&S[0][0], 128, 8, 128, 7, -1.0f, tid, 256);
  for (int idx = tid; idx < 1024; idx += 256){
    int f = idx >> 7, k1 = idx & 127;
    rowp[f*128 + k1] = S[f][brevn((unsigned)k1, 7)];
  }
}

// pointwise: split packed spectrum Z into D,R; C = D*R; write C[k] and conj at mirror.
// thread owns pair (k, NF-k); k = k2 + 1024*k1, addr = k2*128 + k1; cover k1 in [0,64)
extern "C" __global__ void __launch_bounds__(256) k_point(float2* __restrict__ buf){
  int rl = blockIdx.y;
  int t = blockIdx.x*256 + threadIdx.x;   // 0..65535
  int k2 = t >> 6, k1 = t & 63;
  float2* rowp = buf + (size_t)rl*NFB;
  if (k2 == 0){
    if (k1 == 0){
      float2 z0 = rowp[0];  rowp[0]  = make_float2(z0.x*z0.y, 0.f);   // k=0
      float2 zh = rowp[64]; rowp[64] = make_float2(zh.x*zh.y, 0.f);   // k=NF/2
    } else {
      float2 z = rowp[k1], zm = rowp[128 - k1];
      float Dx = 0.5f*(z.x + zm.x), Dy = 0.5f*(z.y - zm.y);
      float Rx = 0.5f*(z.y + zm.y), Ry = -0.5f*(z.x - zm.x);
      float Cx = Dx*Rx - Dy*Ry, Cy = Dx*Ry + Dy*Rx;
      rowp[k1]       = make_float2(Cx,  Cy);
      rowp[128 - k1] = make_float2(Cx, -Cy);
    }
  } else {
    int a  = k2*128 + k1;
    int am = (1024 - k2)*128 + (127 - k1);
    float2 z = rowp[a], zm = rowp[am];
    float Dx = 0.5f*(z.x + zm.x), Dy = 0.5f*(z.y - zm.y);
    float Rx = 0.5f*(z.y + zm.y), Ry = -0.5f*(z.x - zm.x);
    float Cx = Dx*Rx - Dy*Ry, Cy = Dx*Ry + Dy*Rx;
    rowp[a]  = make_float2(Cx,  Cy);
    rowp[am] = make_float2(Cx, -Cy);
  }
}

// inv1: per k2-row, inverse 128-pt FFT over k1 -> B[k2][n1], * W_NF^(+n1*k2), in place
extern "C" __global__ void __launch_bounds__(256) k_inv1(float2* __restrict__ buf){
  __shared__ float2 S[8][128];
  int rl = blockIdx.y;
  int k2_0 = blockIdx.x * 8;
  float2* rowp = buf + (size_t)rl*NFB + (size_t)k2_0*128;
  int tid = threadIdx.x;
  for (int idx = tid; idx < 1024; idx += 256) S[idx>>7][idx&127] = rowp[idx];
  __syncthreads();
  fft_lds(&S[0][0], 128, 8, 128, 7, +1.0f, tid, 256);
  const float tw = PI2F / (float)NFB;
  for (int idx = tid; idx < 1024; idx += 256){
    int f = idx >> 7, n1 = idx & 127;
    int k2 = k2_0 + f;
    float2 v = S[f][brevn((unsigned)n1, 7)];
    float sn, cs; fsincos(tw * (float)(n1*k2), &sn, &cs);
    rowp[f*128 + n1] = make_float2(v.x*cs - v.y*sn, v.x*sn + v.y*cs);
  }
}

// inv2: per n1, inverse 1024-pt FFT over k2 -> c[n1+128*n2]; fuse |c - mix| reduction
extern "C" __global__ void __launch_bounds__(256) k_inv2(
    const float* __restrict__ mix, float2* __restrict__ buf, int row0){
  __shared__ float2 S[8][1024];
  int rl = blockIdx.y;
  int r = row0 + rl;
  int n1_0 = blockIdx.x * 8;
  int tid = threadIdx.x;
  float2* rowp = buf + (size_t)rl*NFB;
  for (int idx = tid; idx < 8192; idx += 256){
    int f = idx & 7, k2 = idx >> 3;
    S[f][k2] = rowp[(size_t)k2*128 + n1_0 + f];
  }
  __syncthreads();
  fft_lds(&S[0][0], 1024, 8, 1024, 10, +1.0f, tid, 256);
  const float* mr = mix + (size_t)r*TLEN;
  const float invn = 1.0f/(float)NFB;
  float acc = 0.f;
  for (int idx = tid; idx < 8192; idx += 256){
    int f = idx & 7, n2 = idx >> 3;
    if (n2 < 500){
      float c = S[f][brevn((unsigned)n2, 10)].x * invn;
      int n = n1_0 + f + 128*n2;
      acc += fabsf(c - mr[n]);
    }
  }
  __syncthreads();
  float v = wred(acc);
  float* Sf = (float*)&S[0][0];   // reuse LDS for the cross-wave reduce
  int lane = tid & 63, wid = tid >> 6;
  if (lane == 0) Sf[wid] = v;
  __syncthreads();
  if (tid == 0){
    int bank = (blockIdx.x + blockIdx.y*16) & 63;
    atomAddD(&g_part[bank][10], (double)(Sf[0]+Sf[1]+Sf[2]+Sf[3]));
  }
}

// ---------------- combine ----------------
extern "C" __global__ void __launch_bounds__(64) k_finalize(float* __restrict__ out){
  __shared__ double s[12];
  int t = threadIdx.x;
  if (t < 12){
    double v = 0.0;
    for (int b = 0; b < 64; ++b) v += g_part[b][t];
    s[t] = v;
  }
  __syncthreads();
  if (t == 0){
    double dt = s[0] / 4096000.0;
    double rt = s[1] / 4096000.0;
    double sp = s[2] / 4096000.0;
    double e0 = s[3] / 1024000.0, e1 = s[4] / 1024000.0;
    double e2 = s[5] / 1024000.0, e3 = s[6] / 1024000.0;
    double dec = fmax(e1 - 0.8*e0, 0.0) + fmax(e2 - 0.8*e1, 0.0) + fmax(e3 - 0.8*e2, 0.0);
    double c1 = 8240832.0;              // 64*513*251
    double freq = s[7]/c1 + 0.1*(1.0 - s[8]/c1);
    double mel  = s[9] / 1285120.0;     // 64*80*251
    double cons = s[10] / 4096000.0;
    double total = 3.0*(dt + 0.5*freq + 0.3*mel)
                 + (rt + 0.1*(sp + dec))
                 + 0.2*cons;
    out[0] = (float)total;
  }
}

extern "C" void kernel_launch(void* const* d_in, const int* in_sizes, int n_in,
                              void* d_out, int out_size, void* d_ws, size_t ws_size,
                              hipStream_t stream){
  const float* pd = (const float*)d_in[0];
  const float* pr = (const float*)d_in[1];
  const float* td = (const float*)d_in[2];
  const float* tr = (const float*)d_in[3];
  const float* mx = (const float*)d_in[4];
  float* out = (float*)d_out;
  float2* buf = (float2*)d_ws;

  size_t rowBytes = (size_t)NFB * sizeof(float2);     // 1 MiB per row
  int maxrows = (int)(ws_size / rowBytes);
  if (maxrows > ROWS) maxrows = ROWS;
  if (maxrows < 1) maxrows = 1;

  hipLaunchKernelGGL(k_init, dim3(3), dim3(256), 0, stream);
  hipLaunchKernelGGL(k_time, dim3(2048), dim3(256), 0, stream, pd, td, pr, tr);
  hipLaunchKernelGGL(k_stft, dim3(ROWS*NFR), dim3(256), 0, stream, pd, td);
  for (int row0 = 0; row0 < ROWS; row0 += maxrows){
    int nr = ROWS - row0; if (nr > maxrows) nr = maxrows;
    hipLaunchKernelGGL(k_fwd1,  dim3(16, nr),  dim3(256), 0, stream, pd, pr, buf, row0);
    hipLaunchKernelGGL(k_fwd2,  dim3(128, nr), dim3(256), 0, stream, buf);
    hipLaunchKernelGGL(k_point, dim3(256, nr), dim3(256), 0, stream, buf);
    hipLaunchKernelGGL(k_inv1,  dim3(128, nr), dim3(256), 0, stream, buf);
    hipLaunchKernelGGL(k_inv2,  dim3(16, nr),  dim3(256), 0, stream, mx, buf, row0);
  }
  hipLaunchKernelGGL(k_finalize, dim3(1), dim3(64), 0, stream, out);
}